// Round 19
// baseline (42.467 us; speedup 1.0000x reference)
//
#include <hip/hip_runtime.h>

#define NSTEP 2047

typedef float v4f __attribute__((ext_vector_type(4), aligned(4)));

__device__ __forceinline__ float fexp2(float x){float r;asm("v_exp_f32 %0, %1":"=v"(r):"v"(x));return r;}
__device__ __forceinline__ float frcp (float x){float r;asm("v_rcp_f32 %0, %1":"=v"(r):"v"(x));return r;}

// 16 chunks, W=126, V=120, perfectly balanced: every wave runs 246 steps.
// wid = c*64+g -> XCD = g%8 for all chunks of a sample group (r14-proven).
// t_s = 120c+1 (o0 = 120c, mod-8 aligned -> float4 stream).
// c=0: exact from t=1, acc t=1..246.
// c=1..14: warm t in [120c+1, 120c+126], acc t in [120c+127, 120c+246].
// c=15: warm t in [1801,1926], acc t=1927..2045, then t=2046 (no acc) -> x_T.
// Partial costs are atomicAdd'ed straight into out[b] (out zeroed by memset).
__global__ __launch_bounds__(64, 1)
void cstr_chunk(const float* __restrict__ w, const float* __restrict__ Kp,
                const float* __restrict__ Lp, const float* __restrict__ Mp,
                const float* __restrict__ Mop, float* __restrict__ out)
{
    const int lane = threadIdx.x;
    const int wid  = blockIdx.x;               // 1024 waves
    const int c    = wid >> 6;                 // chunk 0..15 (wave-uniform)
    const int g    = wid & 63;                 // sample group; XCD = g%8
    const int b    = g * 64 + lane;            // sample 0..4095

    constexpr float Hc=0.01f, Acf=0.99f, Bcf=-0.5f*Hc*Hc;
    constexpr float T2L=2.8853900817779268f, L2E=1.4426950408889634f;
    constexpr float SC1=0.5f*Hc, SCT=SC1*T2L;

    const float K0=Kp[0], K1=Kp[1], MoV=Mop[0];
    const float c00=Lp[0], c11=Lp[5], c22=Lp[10], c33=Lp[15];
    const float c01=Lp[1]+Lp[4], c02=Lp[2]+Lp[8], c03=Lp[3]+Lp[12];
    const float c12=Lp[6]+Lp[9], c13=Lp[7]+Lp[13], c23=Lp[11]+Lp[14];
    const float m0=Mp[0], m1=Mp[1], m2=Mp[2], m3=Mp[3];
    const float sB = MoV * L2E;

    const int o0 = 120 * c;                    // t_s - 1

    const float* rw0 = w + (size_t)b * (2*NSTEP);
    const float* rw1 = rw0 + NSTEP;

    const float w10 = rw0[0], w20 = rw1[0];
    // tail words (o0+244..o0+246; c=15 max = 2046, in-bounds) loaded early
    float fa0 = rw0[o0+244], fa1 = rw0[o0+245], fa2 = rw0[o0+246];
    float fb0 = rw1[o0+244], fb1 = rw1[o0+245], fb2 = rw1[o0+246];
    const float th1 = 1.0f - 2.0f*frcp(fexp2(T2L) + 1.0f);   // tanh(1)

    // ---- state init ----
    float x1, x2, xh1, U, THh1;
    if (c == 0) {
        x1 = Acf + Hc*SC1 + Hc*K0 + w10;
        x2 = Bcf - Hc*th1 + 0.5f*Hc*K0 + w20;
        xh1 = 1.0f; U = K0; THh1 = th1;
    } else { x1 = 0.0f; x2 = 0.0f; xh1 = 0.0f; U = 0.0f; THh1 = 0.0f; }
    float xh2 = 0.0f;
    float THh2 = 1.0f - 2.0f*frcp(fexp2(SCT) + 1.0f);
    float THx1 = 1.0f - 2.0f*frcp(fexp2(T2L*x1) + 1.0f);
    float THx2 = 1.0f - 2.0f*frcp(fexp2(__builtin_fmaf(T2L,x2,SCT)) + 1.0f);
    float delta = 0.5f, PS = 0.0f;
    float SXX1=0.0f, SXX2=0.0f, SXY=0.0f, SD=0.0f;

    auto step = [&](float w1v, float w2v, bool acc, bool exact) {
        const float hu = Hc*U;
        const float f1 = __builtin_fmaf(Acf, xh1, __builtin_fmaf(Hc, THh2, hu));
        const float f2 = __builtin_fmaf(Acf, xh2, __builtin_fmaf(-Hc, THh1,
                          __builtin_fmaf(0.5f, hu, Bcf)));
        float g1 = __builtin_fmaf(c00,x1,m0); g1=__builtin_fmaf(c01,x2,g1);
        g1=__builtin_fmaf(c02,f1,g1); g1=__builtin_fmaf(c03,f2,g1);
        float g2 = __builtin_fmaf(c11,x2,m1); g2=__builtin_fmaf(c12,f1,g2);
        g2=__builtin_fmaf(c13,f2,g2);
        float g3 = __builtin_fmaf(c22,f1,m2); g3=__builtin_fmaf(c23,f2,g3);
        float g4 = __builtin_fmaf(c33,f2,m3);
        const float ps = __builtin_fmaf(x1,g1, __builtin_fmaf(x2,g2,
                          __builtin_fmaf(f1,g3, f2*g4)));
        if (exact) {
            delta = frcp(1.0f + fexp2(__builtin_fmaf(-L2E, ps, -sB)));
        } else {  // 2nd-order sigmoid propagation
            const float dphi = ps - PS;
            const float sd = __builtin_fmaf(-delta, delta, delta);
            const float qq = __builtin_fmaf(dphi, 0.5f - delta, 1.0f);
            delta = __builtin_fmaf(dphi*sd, qq, delta);
        }
        PS = ps;
        const float d1 = x1 - f1, d2 = x2 - f2;
        const float nh1 = __builtin_fmaf(delta, d1, f1);
        const float nh2 = __builtin_fmaf(delta, d2, f2);
        const float un  = __builtin_fmaf(K1, nh2, K0*nh1);
        if (acc) {
            SXX1 = __builtin_fmaf(x1, x1, SXX1);
            SXX2 = __builtin_fmaf(x2, x2, SXX2);
            SXY  = __builtin_fmaf(x1, x2, SXY);
            SD  += delta;
        }
        const float hun = Hc*un;
        const float nx1 = __builtin_fmaf(Acf, x1, __builtin_fmaf(Hc, THx2, w1v + hun));
        const float nx2 = __builtin_fmaf(Acf, x2, __builtin_fmaf(-Hc, THx1,
                           __builtin_fmaf(0.5f, hun, w2v + Bcf)));
        if (exact) {
            THh1 = __builtin_fmaf(-2.0f, frcp(fexp2(T2L*nh1)+1.0f), 1.0f);
            THh2 = __builtin_fmaf(-2.0f, frcp(fexp2(__builtin_fmaf(T2L,nh2,SCT))+1.0f), 1.0f);
            THx1 = __builtin_fmaf(-2.0f, frcp(fexp2(T2L*nx1)+1.0f), 1.0f);
            THx2 = __builtin_fmaf(-2.0f, frcp(fexp2(__builtin_fmaf(T2L,nx2,SCT))+1.0f), 1.0f);
        } else {  // 1st-order tanh propagation
            { const float dS=nh1-xh1, sc=__builtin_fmaf(-THh1,THh1,1.0f);
              THh1=__builtin_fmaf(dS, sc, THh1); }
            { const float dS=nh2-xh2, sc=__builtin_fmaf(-THh2,THh2,1.0f);
              THh2=__builtin_fmaf(dS, sc, THh2); }
            { const float dS=nx1-x1,  sc=__builtin_fmaf(-THx1,THx1,1.0f);
              THx1=__builtin_fmaf(dS, sc, THx1); }
            { const float dS=nx2-x2,  sc=__builtin_fmaf(-THx2,THx2,1.0f);
              THx2=__builtin_fmaf(dS, sc, THx2); }
        }
        x1=nx1; x2=nx2; xh1=nh1; xh2=nh2; U=un;
    };

    // ---- rolling 16B float4 stream: regs hold words [o..o+11], advance 8 ----
    const float* q0 = rw0 + o0;
    const float* q1 = rw1 + o0;
    v4f Wa0 = *(const v4f*)(q0);     v4f Wb0 = *(const v4f*)(q1);
    v4f Wa1 = *(const v4f*)(q0 + 4); v4f Wb1 = *(const v4f*)(q1 + 4);
    v4f Wa2 = *(const v4f*)(q0 + 8); v4f Wb2 = *(const v4f*)(q1 + 8);
    const float* p0 = q0 + 12;
    const float* p1 = q1 + 12;

#define STEPS8(f0,f1_,f2_,f3_,f4_,f5_,f6_,f7_) \
        step(Wa0.y, Wb0.y, f0,  true ); \
        step(Wa0.z, Wb0.z, f1_, false); \
        step(Wa0.w, Wb0.w, f2_, false); \
        step(Wa1.x, Wb1.x, f3_, false); \
        step(Wa1.y, Wb1.y, f4_, false); \
        step(Wa1.z, Wb1.z, f5_, false); \
        step(Wa1.w, Wb1.w, f6_, false); \
        step(Wa2.x, Wb2.x, f7_, false);

    auto runblk = [&](bool ACC) {   // 8 steps + next-block prefetch (max word o0+243)
        const v4f Na1 = *(const v4f*)(p0); const v4f Na2 = *(const v4f*)(p0 + 4);
        const v4f Nb1 = *(const v4f*)(p1); const v4f Nb2 = *(const v4f*)(p1 + 4);
        STEPS8(ACC,ACC,ACC,ACC,ACC,ACC,ACC,ACC)
        Wa0 = Wa2; Wa1 = Na1; Wa2 = Na2;
        Wb0 = Wb2; Wb1 = Nb1; Wb2 = Nb2;
        p0 += 8; p1 += 8;
    };
    auto runblk_mix = [&]() {       // steps 121..128: warm 121..126, acc 127,128
        const v4f Na1 = *(const v4f*)(p0); const v4f Na2 = *(const v4f*)(p0 + 4);
        const v4f Nb1 = *(const v4f*)(p1); const v4f Nb2 = *(const v4f*)(p1 + 4);
        STEPS8(false,false,false,false,false,false,true,true)
        Wa0 = Wa2; Wa1 = Na1; Wa2 = Na2;
        Wb0 = Wb2; Wb1 = Nb1; Wb2 = Nb2;
        p0 += 8; p1 += 8;
    };

    if (c == 0) {
        for (int k = 0; k < 29; ++k) runblk(true);    // acc steps 1..232
    } else {
        for (int k = 0; k < 15; ++k) runblk(false);   // warm steps 1..120
        runblk_mix();                                  // steps 121..128
        for (int k = 0; k < 13; ++k) runblk(true);    // acc steps 129..232
    }
    // reg block: steps 233..240 (words o0+233..240 in regs), all acc
    STEPS8(true,true,true,true,true,true,true,true)

    // final 6 steps: 241..246 (words o0+241..243 in regs, 244..246 preloaded)
    const bool late = (c == 15);
    step(Wa2.y, Wb2.y, true, true );    // step 241 (fresh exact)
    step(Wa2.z, Wb2.z, true, false);    // 242
    step(Wa2.w, Wb2.w, true, false);    // 243
    step(fa0,   fb0,   true, false);    // 244
    step(fa1,   fb1,   true, false);    // 245
    step(fa2,   fb2,   !late, false);   // 246; c=15: t=2046, no acc
    const float xt1 = x1, xt2 = x2;     // c=15: x_T

    // per-chunk partial cost -> atomic accumulate into out[b]
    float P = SXX1 + SXX2 + SD;
    P = __builtin_fmaf(K0*K0, SXX1, P);
    P = __builtin_fmaf(2.0f*K0*K1, SXY, P);
    P = __builtin_fmaf(K1*K1, SXX2, P);
    if (c == 0)  P += 2.0f + K0*K0;                 // t=0 terms
    if (late)    P += 10.0f * (xt1*xt1 + xt2*xt2);  // final cost
    atomicAdd(&out[b], P);
#undef STEPS8
}

extern "C" void kernel_launch(void* const* d_in, const int* in_sizes, int n_in,
                              void* d_out, int out_size, void* d_ws, size_t ws_size,
                              hipStream_t stream) {
    const float* w  = (const float*)d_in[0];
    const float* K  = (const float*)d_in[1];
    const float* L  = (const float*)d_in[2];
    const float* M  = (const float*)d_in[3];
    const float* Mo = (const float*)d_in[4];
    float* out = (float*)d_out;
    hipMemsetAsync(out, 0, (size_t)out_size * sizeof(float), stream);
    cstr_chunk<<<dim3(1024), dim3(64), 0, stream>>>(w, K, L, M, Mo, out);
}

// Round 20
// 39.662 us; speedup vs baseline: 1.0707x; 1.0707x over previous
//
#include <hip/hip_runtime.h>

#define NSTEP 2047

typedef float v4f __attribute__((ext_vector_type(4), aligned(4)));

__device__ __forceinline__ float fexp2(float x){float r;asm("v_exp_f32 %0, %1":"=v"(r):"v"(x));return r;}
__device__ __forceinline__ float frcp (float x){float r;asm("v_rcp_f32 %0, %1":"=v"(r):"v"(x));return r;}

// 16 chunks, W=126, V=120, perfectly balanced: every wave runs 246 steps.
// wid = c*64+g -> XCD = g%8 for all chunks of a sample group (r14-proven).
// t_s = 120c+1 (o0 = 120c, mod-8 aligned -> float4 stream).
// c=0: exact from t=1, acc t=1..246.
// c=1..14: warm t in [120c+1, 120c+126], acc t in [120c+127, 120c+246].
// c=15: warm t in [1801,1926], acc t=1927..2045, then t=2046 (no acc) -> x_T.
__global__ __launch_bounds__(64, 1)
void cstr_chunk(const float* __restrict__ w, const float* __restrict__ Kp,
                const float* __restrict__ Lp, const float* __restrict__ Mp,
                const float* __restrict__ Mop, float* __restrict__ ws)
{
    const int lane = threadIdx.x;
    const int wid  = blockIdx.x;               // 1024 waves
    const int c    = wid >> 6;                 // chunk 0..15 (wave-uniform)
    const int g    = wid & 63;                 // sample group; XCD = g%8
    const int b    = g * 64 + lane;            // sample 0..4095

    constexpr float Hc=0.01f, Acf=0.99f, Bcf=-0.5f*Hc*Hc;
    constexpr float T2L=2.8853900817779268f, L2E=1.4426950408889634f;
    constexpr float SC1=0.5f*Hc, SCT=SC1*T2L;

    const float K0=Kp[0], K1=Kp[1], MoV=Mop[0];
    const float c00=Lp[0], c11=Lp[5], c22=Lp[10], c33=Lp[15];
    const float c01=Lp[1]+Lp[4], c02=Lp[2]+Lp[8], c03=Lp[3]+Lp[12];
    const float c12=Lp[6]+Lp[9], c13=Lp[7]+Lp[13], c23=Lp[11]+Lp[14];
    const float m0=Mp[0], m1=Mp[1], m2=Mp[2], m3=Mp[3];
    const float sB = MoV * L2E;

    const int o0 = 120 * c;                    // t_s - 1

    const float* rw0 = w + (size_t)b * (2*NSTEP);
    const float* rw1 = rw0 + NSTEP;

    const float w10 = rw0[0], w20 = rw1[0];
    // tail words (o0+244..o0+246; c=15 max = 2046, in-bounds) loaded early
    float fa0 = rw0[o0+244], fa1 = rw0[o0+245], fa2 = rw0[o0+246];
    float fb0 = rw1[o0+244], fb1 = rw1[o0+245], fb2 = rw1[o0+246];
    const float th1 = 1.0f - 2.0f*frcp(fexp2(T2L) + 1.0f);   // tanh(1)

    // ---- state init ----
    float x1, x2, xh1, U, THh1;
    if (c == 0) {
        x1 = Acf + Hc*SC1 + Hc*K0 + w10;
        x2 = Bcf - Hc*th1 + 0.5f*Hc*K0 + w20;
        xh1 = 1.0f; U = K0; THh1 = th1;
    } else { x1 = 0.0f; x2 = 0.0f; xh1 = 0.0f; U = 0.0f; THh1 = 0.0f; }
    float xh2 = 0.0f;
    float THh2 = 1.0f - 2.0f*frcp(fexp2(SCT) + 1.0f);
    float THx1 = 1.0f - 2.0f*frcp(fexp2(T2L*x1) + 1.0f);
    float THx2 = 1.0f - 2.0f*frcp(fexp2(__builtin_fmaf(T2L,x2,SCT)) + 1.0f);
    float delta = 0.5f, PS = 0.0f;
    float SXX1=0.0f, SXX2=0.0f, SXY=0.0f, SD=0.0f;

    auto step = [&](float w1v, float w2v, bool acc, bool exact) {
        const float hu = Hc*U;
        const float f1 = __builtin_fmaf(Acf, xh1, __builtin_fmaf(Hc, THh2, hu));
        const float f2 = __builtin_fmaf(Acf, xh2, __builtin_fmaf(-Hc, THh1,
                          __builtin_fmaf(0.5f, hu, Bcf)));
        float g1 = __builtin_fmaf(c00,x1,m0); g1=__builtin_fmaf(c01,x2,g1);
        g1=__builtin_fmaf(c02,f1,g1); g1=__builtin_fmaf(c03,f2,g1);
        float g2 = __builtin_fmaf(c11,x2,m1); g2=__builtin_fmaf(c12,f1,g2);
        g2=__builtin_fmaf(c13,f2,g2);
        float g3 = __builtin_fmaf(c22,f1,m2); g3=__builtin_fmaf(c23,f2,g3);
        float g4 = __builtin_fmaf(c33,f2,m3);
        const float ps = __builtin_fmaf(x1,g1, __builtin_fmaf(x2,g2,
                          __builtin_fmaf(f1,g3, f2*g4)));
        if (exact) {
            delta = frcp(1.0f + fexp2(__builtin_fmaf(-L2E, ps, -sB)));
        } else {  // 2nd-order sigmoid propagation
            const float dphi = ps - PS;
            const float sd = __builtin_fmaf(-delta, delta, delta);
            const float qq = __builtin_fmaf(dphi, 0.5f - delta, 1.0f);
            delta = __builtin_fmaf(dphi*sd, qq, delta);
        }
        PS = ps;
        const float d1 = x1 - f1, d2 = x2 - f2;
        const float nh1 = __builtin_fmaf(delta, d1, f1);
        const float nh2 = __builtin_fmaf(delta, d2, f2);
        const float un  = __builtin_fmaf(K1, nh2, K0*nh1);
        if (acc) {
            SXX1 = __builtin_fmaf(x1, x1, SXX1);
            SXX2 = __builtin_fmaf(x2, x2, SXX2);
            SXY  = __builtin_fmaf(x1, x2, SXY);
            SD  += delta;
        }
        const float hun = Hc*un;
        const float nx1 = __builtin_fmaf(Acf, x1, __builtin_fmaf(Hc, THx2, w1v + hun));
        const float nx2 = __builtin_fmaf(Acf, x2, __builtin_fmaf(-Hc, THx1,
                           __builtin_fmaf(0.5f, hun, w2v + Bcf)));
        if (exact) {
            THh1 = __builtin_fmaf(-2.0f, frcp(fexp2(T2L*nh1)+1.0f), 1.0f);
            THh2 = __builtin_fmaf(-2.0f, frcp(fexp2(__builtin_fmaf(T2L,nh2,SCT))+1.0f), 1.0f);
            THx1 = __builtin_fmaf(-2.0f, frcp(fexp2(T2L*nx1)+1.0f), 1.0f);
            THx2 = __builtin_fmaf(-2.0f, frcp(fexp2(__builtin_fmaf(T2L,nx2,SCT))+1.0f), 1.0f);
        } else {  // 1st-order tanh propagation
            { const float dS=nh1-xh1, sc=__builtin_fmaf(-THh1,THh1,1.0f);
              THh1=__builtin_fmaf(dS, sc, THh1); }
            { const float dS=nh2-xh2, sc=__builtin_fmaf(-THh2,THh2,1.0f);
              THh2=__builtin_fmaf(dS, sc, THh2); }
            { const float dS=nx1-x1,  sc=__builtin_fmaf(-THx1,THx1,1.0f);
              THx1=__builtin_fmaf(dS, sc, THx1); }
            { const float dS=nx2-x2,  sc=__builtin_fmaf(-THx2,THx2,1.0f);
              THx2=__builtin_fmaf(dS, sc, THx2); }
        }
        x1=nx1; x2=nx2; xh1=nh1; xh2=nh2; U=un;
    };

    // ---- rolling 16B float4 stream: regs hold words [o..o+11], advance 8 ----
    const float* q0 = rw0 + o0;
    const float* q1 = rw1 + o0;
    v4f Wa0 = *(const v4f*)(q0);     v4f Wb0 = *(const v4f*)(q1);
    v4f Wa1 = *(const v4f*)(q0 + 4); v4f Wb1 = *(const v4f*)(q1 + 4);
    v4f Wa2 = *(const v4f*)(q0 + 8); v4f Wb2 = *(const v4f*)(q1 + 8);
    const float* p0 = q0 + 12;
    const float* p1 = q1 + 12;

#define STEPS8(f0,f1_,f2_,f3_,f4_,f5_,f6_,f7_) \
        step(Wa0.y, Wb0.y, f0,  true ); \
        step(Wa0.z, Wb0.z, f1_, false); \
        step(Wa0.w, Wb0.w, f2_, false); \
        step(Wa1.x, Wb1.x, f3_, false); \
        step(Wa1.y, Wb1.y, f4_, false); \
        step(Wa1.z, Wb1.z, f5_, false); \
        step(Wa1.w, Wb1.w, f6_, false); \
        step(Wa2.x, Wb2.x, f7_, false);

    auto runblk = [&](bool ACC) {   // 8 steps + next-block prefetch (max word o0+243)
        const v4f Na1 = *(const v4f*)(p0); const v4f Na2 = *(const v4f*)(p0 + 4);
        const v4f Nb1 = *(const v4f*)(p1); const v4f Nb2 = *(const v4f*)(p1 + 4);
        STEPS8(ACC,ACC,ACC,ACC,ACC,ACC,ACC,ACC)
        Wa0 = Wa2; Wa1 = Na1; Wa2 = Na2;
        Wb0 = Wb2; Wb1 = Nb1; Wb2 = Nb2;
        p0 += 8; p1 += 8;
    };
    auto runblk_mix = [&]() {       // steps 121..128: warm 121..126, acc 127,128
        const v4f Na1 = *(const v4f*)(p0); const v4f Na2 = *(const v4f*)(p0 + 4);
        const v4f Nb1 = *(const v4f*)(p1); const v4f Nb2 = *(const v4f*)(p1 + 4);
        STEPS8(false,false,false,false,false,false,true,true)
        Wa0 = Wa2; Wa1 = Na1; Wa2 = Na2;
        Wb0 = Wb2; Wb1 = Nb1; Wb2 = Nb2;
        p0 += 8; p1 += 8;
    };

    if (c == 0) {
        for (int k = 0; k < 29; ++k) runblk(true);    // acc steps 1..232
    } else {
        for (int k = 0; k < 15; ++k) runblk(false);   // warm steps 1..120
        runblk_mix();                                  // steps 121..128
        for (int k = 0; k < 13; ++k) runblk(true);    // acc steps 129..232
    }
    // reg block: steps 233..240 (words o0+233..240 in regs), all acc
    STEPS8(true,true,true,true,true,true,true,true)

    // final 6 steps: 241..246 (words o0+241..243 in regs, 244..246 preloaded)
    const bool late = (c == 15);
    step(Wa2.y, Wb2.y, true, true );    // step 241 (fresh exact)
    step(Wa2.z, Wb2.z, true, false);    // 242
    step(Wa2.w, Wb2.w, true, false);    // 243
    step(fa0,   fb0,   true, false);    // 244
    step(fa1,   fb1,   true, false);    // 245
    step(fa2,   fb2,   !late, false);   // 246; c=15: t=2046, no acc
    const float xt1 = x1, xt2 = x2;     // c=15: x_T

    // per-chunk partial cost -> ws[c][b]
    float P = SXX1 + SXX2 + SD;
    P = __builtin_fmaf(K0*K0, SXX1, P);
    P = __builtin_fmaf(2.0f*K0*K1, SXY, P);
    P = __builtin_fmaf(K1*K1, SXX2, P);
    if (c == 0)  P += 2.0f + K0*K0;                 // t=0 terms
    if (late)    P += 10.0f * (xt1*xt1 + xt2*xt2);  // final cost
    ws[c * 4096 + b] = P;
#undef STEPS8
}

__global__ __launch_bounds__(64)
void cstr_reduce(const float* __restrict__ ws, float* __restrict__ out)
{
    const int b = blockIdx.x * 64 + threadIdx.x;   // 0..4095
    float s = 0.0f;
#pragma unroll
    for (int c = 0; c < 16; ++c) s += ws[c * 4096 + b];
    out[b] = s;
}

extern "C" void kernel_launch(void* const* d_in, const int* in_sizes, int n_in,
                              void* d_out, int out_size, void* d_ws, size_t ws_size,
                              hipStream_t stream) {
    const float* w  = (const float*)d_in[0];
    const float* K  = (const float*)d_in[1];
    const float* L  = (const float*)d_in[2];
    const float* M  = (const float*)d_in[3];
    const float* Mo = (const float*)d_in[4];
    float* out = (float*)d_out;
    float* ws  = (float*)d_ws;                     // 16*4096*4 B = 256 KB
    cstr_chunk <<<dim3(1024), dim3(64), 0, stream>>>(w, K, L, M, Mo, ws);
    cstr_reduce<<<dim3(64),   dim3(64), 0, stream>>>(ws, out);
}